// Round 2
// baseline (696.441 us; speedup 1.0000x reference)
//
#include <hip/hip_runtime.h>
#include <hip/hip_cooperative_groups.h>
#include <cstdint>
#include <cstddef>

namespace cg = cooperative_groups;

typedef __bf16 bf16x8 __attribute__((ext_vector_type(8)));
typedef float f32x4 __attribute__((ext_vector_type(4)));
typedef unsigned short ushortx4 __attribute__((ext_vector_type(4)));

// float -> bf16, round-half-up
__device__ __forceinline__ unsigned short f2bf(float f) {
  union { float f; unsigned int u; } v; v.f = f;
  return (unsigned short)((v.u + 0x8000u) >> 16);
}

// GELU via sigmoid identity (verified in prior rounds)
__device__ __forceinline__ float gelu_s(float x) {
  float x2 = x * x;
  float p = __builtin_fmaf(x2, -0.10294324f, -2.30220819f);
  float e = __builtin_amdgcn_exp2f(x * p);
  return x * __builtin_amdgcn_rcpf(1.0f + e);
}

// async global->LDS, 16B/lane. LDS dest is wave-uniform base + lane*16.
#define GLOAD16(gsrc, ldst)                                                  \
  __builtin_amdgcn_global_load_lds(                                          \
      (const __attribute__((address_space(1))) unsigned int*)(gsrc),         \
      (__attribute__((address_space(3))) unsigned int*)(uintptr_t)(          \
          (char*)(ldst)),                                                    \
      16, 0, 0)

// Swizzled tile: 16B chunk (row R, col8 C in [0,8)) at
// (R>>5)*4096 + ((R&31)*8 + (C ^ (R&7)))*16. Staging lane tid sources col8
// (tid&7)^((tid>>3)&7); 16-row fragment reads hit all 8 bank quads.
#define SWZ_FRAG(base, R, C8)                                                \
  (*(const bf16x8*)((base) + (((R) >> 5) * 4096) +                           \
                    ((((R)&31) * 8 + ((C8) ^ ((R)&7))) * 16)))

// ---------------------------------------------------------------------------
// Tile bodies (byte-identical math to the passing round-1 kernel)
// ---------------------------------------------------------------------------
__device__ __forceinline__ void expert_tile(
    int e, int mbase, const unsigned short* __restrict__ zb,
    const unsigned short* __restrict__ w1t, const float* __restrict__ b1,
    const float* __restrict__ w2, const float* __restrict__ b2,
    float* __restrict__ out, char* lds, int tid, int wq, int l15, int l4,
    int c8s) {
  char* ldsB = lds + 16384;
  const unsigned short* ag = zb + (size_t)(mbase + (tid >> 3)) * 512 + c8s;
  const unsigned short* bg = w1t + e * 65536 + (tid >> 3) * 512 + c8s;
  const int wr = wq >> 1;  // row half of this wave
  const int wc = wq & 1;   // col half of this wave
  f32x4 acc[4][4] = {};
  for (int kt = 0; kt < 8; ++kt) {
    const int ko = kt * 64;
#pragma unroll
    for (int it = 0; it < 4; ++it)
      GLOAD16(ag + it * 32 * 512 + ko, lds + it * 4096 + tid * 16);
#pragma unroll
    for (int it = 0; it < 4; ++it)
      GLOAD16(bg + it * 32 * 512 + ko, ldsB + it * 4096 + tid * 16);
    __syncthreads();
#pragma unroll
    for (int ks = 0; ks < 2; ++ks) {
      bf16x8 af[4];
#pragma unroll
      for (int rt = 0; rt < 4; ++rt)
        af[rt] = SWZ_FRAG(lds, wr * 64 + rt * 16 + l15, ks * 4 + l4);
#pragma unroll
      for (int ct = 0; ct < 4; ++ct) {
        bf16x8 bfv = SWZ_FRAG(ldsB, wc * 64 + ct * 16 + l15, ks * 4 + l4);
#pragma unroll
        for (int rt = 0; rt < 4; ++rt)
          acc[rt][ct] = __builtin_amdgcn_mfma_f32_16x16x32_bf16(
              af[rt], bfv, acc[rt][ct], 0, 0, 0);
      }
    }
    __syncthreads();
  }
  // epilogue: partial y over this wave's 64 cols, cross-wave combine
  float b1v[4], w2v[4];
#pragma unroll
  for (int ct = 0; ct < 4; ++ct) {
    int n = wc * 64 + ct * 16 + l15;
    b1v[ct] = b1[e * 128 + n];
    w2v[ct] = w2[e * 128 + n];
  }
  float* ylds = (float*)(lds + 32768);  // [4 waves][64 rows]
#pragma unroll
  for (int rt = 0; rt < 4; ++rt) {
#pragma unroll
    for (int i = 0; i < 4; ++i) {
      float s = 0.0f;
#pragma unroll
      for (int ct = 0; ct < 4; ++ct)
        s += gelu_s(acc[rt][ct][i] + b1v[ct]) * w2v[ct];
#pragma unroll
      for (int off = 1; off < 16; off <<= 1) s += __shfl_xor(s, off, 16);
      if (l15 == 0) ylds[wq * 64 + rt * 16 + l4 * 4 + i] = s;
    }
  }
  __syncthreads();
  if (tid < 128) {
    int rl = tid & 63, half = tid >> 6;
    float y = ylds[half * 128 + rl] + ylds[half * 128 + 64 + rl] + b2[e];
    out[(size_t)2097152 + (size_t)(mbase + half * 64 + rl) * 16 + e] = y;
  }
}

__device__ __forceinline__ void logits_tile(
    int mbase, const unsigned short* __restrict__ zb,
    const unsigned short* __restrict__ wct, const float* __restrict__ bc,
    float* __restrict__ out, char* lds, int tid, int wq, int l15, int l4,
    int c8s) {
  const unsigned short* ag = zb + (size_t)(mbase + (tid >> 3)) * 512 + c8s;
  const unsigned short* wb = wct + l15 * 512 + l4 * 8;  // direct, L2-hot
  f32x4 acc2[2] = {};
  for (int kt = 0; kt < 8; ++kt) {
    const int ko = kt * 64;
#pragma unroll
    for (int it = 0; it < 4; ++it)
      GLOAD16(ag + it * 32 * 512 + ko, lds + it * 4096 + tid * 16);
    bf16x8 bfr0 = *(const bf16x8*)(wb + ko);
    bf16x8 bfr1 = *(const bf16x8*)(wb + ko + 32);
    __syncthreads();
#pragma unroll
    for (int rt = 0; rt < 2; ++rt) {
      bf16x8 a0 = SWZ_FRAG(lds, wq * 32 + rt * 16 + l15, l4);
      acc2[rt] =
          __builtin_amdgcn_mfma_f32_16x16x32_bf16(a0, bfr0, acc2[rt], 0, 0, 0);
      bf16x8 a1 = SWZ_FRAG(lds, wq * 32 + rt * 16 + l15, 4 + l4);
      acc2[rt] =
          __builtin_amdgcn_mfma_f32_16x16x32_bf16(a1, bfr1, acc2[rt], 0, 0, 0);
    }
    __syncthreads();
  }
  float bcv = bc[l15];
#pragma unroll
  for (int rt = 0; rt < 2; ++rt) {
#pragma unroll
    for (int i = 0; i < 4; ++i) {
      int row = wq * 32 + rt * 16 + l4 * 4 + i;
      float lg = acc2[rt][i] + bcv;
      float mx = lg;
#pragma unroll
      for (int off = 1; off < 16; off <<= 1)
        mx = fmaxf(mx, __shfl_xor(mx, off, 16));
      float ex = __expf(lg - mx);
      float sm = ex;
#pragma unroll
      for (int off = 1; off < 16; off <<= 1) sm += __shfl_xor(sm, off, 16);
      size_t ro = (size_t)(mbase + row) * 16 + l15;
      out[ro] = lg;                 // logits
      out[1048576 + ro] = ex / sm;  // p_g
    }
  }
}

// ---------------------------------------------------------------------------
// Cooperative persistent kernel.
// Phase 1: convert z (XCD-affine), W1 transpose, Wc transpose, reset tickets.
// grid.sync with device fences (cross-XCD w1t/wct visibility).
// Phase 2: per-XCD atomic ticket queue over 1088 tiles/XCD, grouped as
//   [logits(m) | expert(m, e=0..15)] so each zb panel is L2-hot for 17 tiles.
// ---------------------------------------------------------------------------
__global__ __launch_bounds__(256, 4) void k_fused(
    const float* __restrict__ z, const float* __restrict__ W1,
    const float* __restrict__ Wc, const float* __restrict__ bc,
    const float* __restrict__ b1, const float* __restrict__ w2,
    const float* __restrict__ b2, unsigned short* __restrict__ zb,
    unsigned short* __restrict__ w1t, unsigned short* __restrict__ wct,
    int* __restrict__ cnt, float* __restrict__ out) {
  __shared__ alignas(16) char lds[33792];
  __shared__ int s_t;
  const int NB = gridDim.x;
  const int b = blockIdx.x;
  const int tid = threadIdx.x;
  const int wq = tid >> 6;
  const int l15 = tid & 15;
  const int l4 = (tid >> 4) & 3;
  const int c8s = (((tid & 7) ^ ((tid >> 3) & 7))) * 8;
  const int xcd = b & 7;
  const int slot = b >> 3;
  const int SX = NB >> 3;

  // ---- phase 1: z -> bf16, XCD-affine (xcd x converts rows it will use) ----
  {
    const float4* z4 = (const float4*)z;
    for (int c = slot; c < 1024; c += SX) {
      size_t base = ((size_t)xcd * 1024 + c) * 1024 + tid;
#pragma unroll
      for (int it = 0; it < 4; ++it) {
        size_t i4 = base + (size_t)it * 256;
        float4 a = z4[i4];
        ushortx4 r;
        r[0] = f2bf(a.x); r[1] = f2bf(a.y); r[2] = f2bf(a.z); r[3] = f2bf(a.w);
        *(ushortx4*)(zb + i4 * 4) = r;
      }
    }
  }
  // W1[g,d,h] -> W1t[g,h,d] via 32x32 LDS tile
  for (int w = b; w < 1024; w += NB) {
    float* tile = (float*)lds;  // [32][33]
    int gg = w >> 6;
    int t6 = w & 63;
    int d0 = (t6 >> 2) * 32;
    int h0 = (t6 & 3) * 32;
    int tx = tid & 31, ty = tid >> 5;
#pragma unroll
    for (int r = 0; r < 4; ++r)
      tile[(r * 8 + ty) * 33 + tx] =
          W1[(gg << 16) + (d0 + r * 8 + ty) * 128 + h0 + tx];
    __syncthreads();
#pragma unroll
    for (int r = 0; r < 4; ++r)
      w1t[(gg << 16) + (h0 + r * 8 + ty) * 512 + d0 + tx] =
          f2bf(tile[tx * 33 + r * 8 + ty]);
    __syncthreads();
  }
  // Wc[d,g] -> Wct[g,d]
  if (b < 32) {
    int i = b * 256 + tid;
    wct[(i & 15) * 512 + (i >> 4)] = f2bf(Wc[i]);
  }
  // reset per-XCD ticket counters (device-scope atomic store)
  if (b == NB - 1 && tid < 8) atomicExch(&cnt[tid], 0);

  __threadfence();
  cg::this_grid().sync();
  __threadfence();

  // ---- phase 2: ticket loop ----
  while (true) {
    if (tid == 0) s_t = atomicAdd(&cnt[xcd], 1);
    __syncthreads();
    int t = s_t;
    if (t >= 1088) break;
    int g = t / 17;
    int r = t - g * 17;
    int mbase = (xcd * 64 + g) * 128;
    if (r == 0)
      logits_tile(mbase, zb, wct, bc, out, lds, tid, wq, l15, l4, c8s);
    else
      expert_tile(r - 1, mbase, zb, w1t, b1, w2, b2, out, lds, tid, wq, l15,
                  l4, c8s);
    // tile bodies contain __syncthreads barriers, so s_t reuse is safe
  }
}

// ---------------------------------------------------------------------------
// Fallback path (proven round-1 kernels) in case cooperative launch is
// unavailable — identical semantics.
// ---------------------------------------------------------------------------
__global__ __launch_bounds__(256) void k_convert(
    const float* __restrict__ z, const float* __restrict__ W1,
    const float* __restrict__ Wc, unsigned short* __restrict__ zb,
    unsigned short* __restrict__ w1t, unsigned short* __restrict__ wct) {
  int bid = blockIdx.x;
  int tid = threadIdx.x;
  if (bid < 8192) {
    const float4* z4 = (const float4*)z;
    size_t base = (size_t)bid * 1024 + tid;
#pragma unroll
    for (int it = 0; it < 4; ++it) {
      size_t i4 = base + (size_t)it * 256;
      float4 a = z4[i4];
      ushortx4 r;
      r[0] = f2bf(a.x); r[1] = f2bf(a.y); r[2] = f2bf(a.z); r[3] = f2bf(a.w);
      *(ushortx4*)(zb + i4 * 4) = r;
    }
  } else if (bid < 8192 + 1024) {
    __shared__ float tile[32][33];
    int b = bid - 8192;
    int gg = b >> 6;
    int t = b & 63;
    int d0 = (t >> 2) * 32;
    int h0 = (t & 3) * 32;
    int tx = tid & 31, ty = tid >> 5;
#pragma unroll
    for (int r = 0; r < 4; ++r)
      tile[r * 8 + ty][tx] = W1[(gg << 16) + (d0 + r * 8 + ty) * 128 + h0 + tx];
    __syncthreads();
#pragma unroll
    for (int r = 0; r < 4; ++r)
      w1t[(gg << 16) + (h0 + r * 8 + ty) * 512 + d0 + tx] =
          f2bf(tile[tx][r * 8 + ty]);
  } else {
#pragma unroll
    for (int j = 0; j < 32; ++j) {
      int i = j * 256 + tid;
      wct[(i & 15) * 512 + (i >> 4)] = f2bf(Wc[i]);
    }
  }
}

__global__ __launch_bounds__(256, 4) void k_main(
    const unsigned short* __restrict__ zb,
    const unsigned short* __restrict__ w1t,
    const unsigned short* __restrict__ wct, const float* __restrict__ bc,
    const float* __restrict__ b1, const float* __restrict__ w2,
    const float* __restrict__ b2, float* __restrict__ out) {
  __shared__ alignas(16) char lds[33792];
  const int tid = threadIdx.x;
  const int wq = tid >> 6;
  const int l15 = tid & 15;
  const int l4 = (tid >> 4) & 3;
  const int c8s = (((tid & 7) ^ ((tid >> 3) & 7))) * 8;
  if (blockIdx.x >= 512) {
    const int eb = blockIdx.x - 512;
    const int idx = (eb & 7) * 1024 + (eb >> 3);
    expert_tile(idx & 15, (idx >> 4) * 128, zb, w1t, b1, w2, b2, out, lds, tid,
                wq, l15, l4, c8s);
  } else {
    logits_tile(blockIdx.x * 128, zb, wct, bc, out, lds, tid, wq, l15, l4,
                c8s);
  }
}

// ---------------------------------------------------------------------------
extern "C" void kernel_launch(void* const* d_in, const int* in_sizes, int n_in,
                              void* d_out, int out_size, void* d_ws,
                              size_t ws_size, hipStream_t stream) {
  const float* z = (const float*)d_in[0];
  const float* Wc = (const float*)d_in[1];
  const float* bc = (const float*)d_in[2];
  const float* W1 = (const float*)d_in[3];
  const float* b1 = (const float*)d_in[4];
  const float* W2 = (const float*)d_in[5];
  const float* b2 = (const float*)d_in[6];
  float* out = (float*)d_out;

  unsigned short* zb = (unsigned short*)d_ws;            // 64 MB
  unsigned short* w1t = zb + (size_t)65536 * 512;        // 2 MB
  unsigned short* wct = w1t + (size_t)16 * 128 * 512;    // 16 KB
  int* cnt = (int*)(wct + (size_t)16 * 512);             // 32 B

  int dev = 0;
  (void)hipGetDevice(&dev);
  int coop = 0;
  (void)hipDeviceGetAttribute(&coop, hipDeviceAttributeCooperativeLaunch, dev);
  int maxb = 0;
  (void)hipOccupancyMaxActiveBlocksPerMultiprocessor(&maxb, k_fused, 256, 0);
  int NB = maxb * 256;
  if (NB > 1024) NB = 1024;
  NB &= ~7;

  bool ok = false;
  if (coop && NB >= 64) {
    void* kargs[] = {(void*)&z,   (void*)&W1,  (void*)&Wc,  (void*)&bc,
                     (void*)&b1,  (void*)&W2,  (void*)&b2,  (void*)&zb,
                     (void*)&w1t, (void*)&wct, (void*)&cnt, (void*)&out};
    hipError_t err = hipLaunchCooperativeKernel(
        (const void*)k_fused, dim3(NB), dim3(256), kargs, 0, stream);
    ok = (err == hipSuccess);
  }
  if (!ok) {
    k_convert<<<8192 + 1024 + 1, 256, 0, stream>>>(z, W1, Wc, zb, w1t, wct);
    k_main<<<512 + 8192, 256, 0, stream>>>(zb, w1t, wct, bc, b1, W2, b2, out);
  }
}

// Round 4
// 367.529 us; speedup vs baseline: 1.8949x; 1.8949x over previous
//
#include <hip/hip_runtime.h>
#include <cstdint>
#include <cstddef>

typedef __bf16 bf16x8 __attribute__((ext_vector_type(8)));
typedef float f32x4 __attribute__((ext_vector_type(4)));
typedef unsigned short ushortx4 __attribute__((ext_vector_type(4)));

// float -> bf16, round-half-up
__device__ __forceinline__ unsigned short f2bf(float f) {
  union { float f; unsigned int u; } v; v.f = f;
  return (unsigned short)((v.u + 0x8000u) >> 16);
}

// GELU via sigmoid identity (verified in prior rounds)
__device__ __forceinline__ float gelu_s(float x) {
  float x2 = x * x;
  float p = __builtin_fmaf(x2, -0.10294324f, -2.30220819f);
  float e = __builtin_amdgcn_exp2f(x * p);
  return x * __builtin_amdgcn_rcpf(1.0f + e);
}

// async global->LDS, 16B/lane. LDS dest is wave-uniform base + lane*16.
#define GLOAD16(gsrc, ldst)                                                  \
  __builtin_amdgcn_global_load_lds(                                          \
      (const __attribute__((address_space(1))) unsigned int*)(gsrc),         \
      (__attribute__((address_space(3))) unsigned int*)(uintptr_t)(          \
          (char*)(ldst)),                                                    \
      16, 0, 0)

// Swizzled tile: 16B chunk (row R, col8 C in [0,8)) at
// (R>>5)*4096 + ((R&31)*8 + (C ^ (R&7)))*16. Staging lane tid sources col8
// (tid&7)^((tid>>3)&7); 16-row fragment reads hit all 8 bank quads.
#define SWZ_FRAG(base, R, C8)                                                \
  (*(const bf16x8*)((base) + (((R) >> 5) * 4096) +                           \
                    ((((R)&31) * 8 + ((C8) ^ ((R)&7))) * 16)))

// ---------------------------------------------------------------------------
// Tile bodies (byte-identical math to the passing round-1 kernel)
// ---------------------------------------------------------------------------
__device__ __forceinline__ void expert_tile(
    int e, int mbase, const unsigned short* __restrict__ zb,
    const unsigned short* __restrict__ w1t, const float* __restrict__ b1,
    const float* __restrict__ w2, const float* __restrict__ b2,
    float* __restrict__ out, char* lds, int tid, int wq, int l15, int l4,
    int c8s) {
  char* ldsB = lds + 16384;
  const unsigned short* ag = zb + (size_t)(mbase + (tid >> 3)) * 512 + c8s;
  const unsigned short* bg = w1t + e * 65536 + (tid >> 3) * 512 + c8s;
  const int wr = wq >> 1;  // row half of this wave
  const int wc = wq & 1;   // col half of this wave
  f32x4 acc[4][4] = {};
  for (int kt = 0; kt < 8; ++kt) {
    const int ko = kt * 64;
#pragma unroll
    for (int it = 0; it < 4; ++it)
      GLOAD16(ag + it * 32 * 512 + ko, lds + it * 4096 + tid * 16);
#pragma unroll
    for (int it = 0; it < 4; ++it)
      GLOAD16(bg + it * 32 * 512 + ko, ldsB + it * 4096 + tid * 16);
    __syncthreads();
#pragma unroll
    for (int ks = 0; ks < 2; ++ks) {
      bf16x8 af[4];
#pragma unroll
      for (int rt = 0; rt < 4; ++rt)
        af[rt] = SWZ_FRAG(lds, wr * 64 + rt * 16 + l15, ks * 4 + l4);
#pragma unroll
      for (int ct = 0; ct < 4; ++ct) {
        bf16x8 bfv = SWZ_FRAG(ldsB, wc * 64 + ct * 16 + l15, ks * 4 + l4);
#pragma unroll
        for (int rt = 0; rt < 4; ++rt)
          acc[rt][ct] = __builtin_amdgcn_mfma_f32_16x16x32_bf16(
              af[rt], bfv, acc[rt][ct], 0, 0, 0);
      }
    }
    __syncthreads();
  }
  // epilogue: partial y over this wave's 64 cols, cross-wave combine
  float b1v[4], w2v[4];
#pragma unroll
  for (int ct = 0; ct < 4; ++ct) {
    int n = wc * 64 + ct * 16 + l15;
    b1v[ct] = b1[e * 128 + n];
    w2v[ct] = w2[e * 128 + n];
  }
  float* ylds = (float*)(lds + 32768);  // [4 waves][64 rows]
#pragma unroll
  for (int rt = 0; rt < 4; ++rt) {
#pragma unroll
    for (int i = 0; i < 4; ++i) {
      float s = 0.0f;
#pragma unroll
      for (int ct = 0; ct < 4; ++ct)
        s += gelu_s(acc[rt][ct][i] + b1v[ct]) * w2v[ct];
#pragma unroll
      for (int off = 1; off < 16; off <<= 1) s += __shfl_xor(s, off, 16);
      if (l15 == 0) ylds[wq * 64 + rt * 16 + l4 * 4 + i] = s;
    }
  }
  __syncthreads();
  if (tid < 128) {
    int rl = tid & 63, half = tid >> 6;
    float y = ylds[half * 128 + rl] + ylds[half * 128 + 64 + rl] + b2[e];
    out[(size_t)2097152 + (size_t)(mbase + half * 64 + rl) * 16 + e] = y;
  }
}

__device__ __forceinline__ void logits_tile(
    int mbase, const unsigned short* __restrict__ zb,
    const unsigned short* __restrict__ wct, const float* __restrict__ bc,
    float* __restrict__ out, char* lds, int tid, int wq, int l15, int l4,
    int c8s) {
  const unsigned short* ag = zb + (size_t)(mbase + (tid >> 3)) * 512 + c8s;
  const unsigned short* wb = wct + l15 * 512 + l4 * 8;  // direct, L2-hot
  f32x4 acc2[2] = {};
  for (int kt = 0; kt < 8; ++kt) {
    const int ko = kt * 64;
#pragma unroll
    for (int it = 0; it < 4; ++it)
      GLOAD16(ag + it * 32 * 512 + ko, lds + it * 4096 + tid * 16);
    bf16x8 bfr0 = *(const bf16x8*)(wb + ko);
    bf16x8 bfr1 = *(const bf16x8*)(wb + ko + 32);
    __syncthreads();
#pragma unroll
    for (int rt = 0; rt < 2; ++rt) {
      bf16x8 a0 = SWZ_FRAG(lds, wq * 32 + rt * 16 + l15, l4);
      acc2[rt] =
          __builtin_amdgcn_mfma_f32_16x16x32_bf16(a0, bfr0, acc2[rt], 0, 0, 0);
      bf16x8 a1 = SWZ_FRAG(lds, wq * 32 + rt * 16 + l15, 4 + l4);
      acc2[rt] =
          __builtin_amdgcn_mfma_f32_16x16x32_bf16(a1, bfr1, acc2[rt], 0, 0, 0);
    }
    __syncthreads();
  }
  float bcv = bc[l15];
#pragma unroll
  for (int rt = 0; rt < 2; ++rt) {
#pragma unroll
    for (int i = 0; i < 4; ++i) {
      int row = wq * 32 + rt * 16 + l4 * 4 + i;
      float lg = acc2[rt][i] + bcv;
      float mx = lg;
#pragma unroll
      for (int off = 1; off < 16; off <<= 1)
        mx = fmaxf(mx, __shfl_xor(mx, off, 16));
      float ex = __expf(lg - mx);
      float sm = ex;
#pragma unroll
      for (int off = 1; off < 16; off <<= 1) sm += __shfl_xor(sm, off, 16);
      size_t ro = (size_t)(mbase + row) * 16 + l15;
      out[ro] = lg;                 // logits
      out[1048576 + ro] = ex / sm;  // p_g
    }
  }
}

// ---------------------------------------------------------------------------
// Conversion v3: fat grid-saturating blocks.
//   bid < 2048          : z -> bf16. 2048 blocks x 256 thr x 16 float4
//                         (4 unrolled batches of 4). 64KB/block, 8 blocks/CU.
//                         Nontemporal z loads (read-once; keep L2 for w1t).
//   bid in [2048, 3072) : W1[g,d,h] -> W1t[g,h,d] via 32x32 LDS tile.
//   bid == 3072         : Wc[d,g] -> Wct[g,d].
// ---------------------------------------------------------------------------
__global__ __launch_bounds__(256, 8) void k_convert(
    const float* __restrict__ z, const float* __restrict__ W1,
    const float* __restrict__ Wc, unsigned short* __restrict__ zb,
    unsigned short* __restrict__ w1t, unsigned short* __restrict__ wct) {
  int bid = blockIdx.x;
  int tid = threadIdx.x;
  if (bid < 2048) {
    const f32x4* z4 = (const f32x4*)z;  // ext_vector type: nontemporal-legal
    size_t base = (size_t)bid * 4096 + tid;
#pragma unroll
    for (int c = 0; c < 4; ++c) {
      f32x4 a[4];
#pragma unroll
      for (int it = 0; it < 4; ++it)
        a[it] = __builtin_nontemporal_load(z4 + base + (c * 4 + it) * 256);
#pragma unroll
      for (int it = 0; it < 4; ++it) {
        ushortx4 r;
        r[0] = f2bf(a[it][0]); r[1] = f2bf(a[it][1]);
        r[2] = f2bf(a[it][2]); r[3] = f2bf(a[it][3]);
        *(ushortx4*)(zb + (base + (c * 4 + it) * 256) * 4) = r;
      }
    }
  } else if (bid < 2048 + 1024) {
    // W1 transpose via 32x32 LDS tile, both sides coalesced
    __shared__ float tile[32][33];
    int b = bid - 2048;
    int gg = b >> 6;
    int t = b & 63;  // 16 d-blk x 4 h-blk
    int d0 = (t >> 2) * 32;
    int h0 = (t & 3) * 32;
    int tx = tid & 31, ty = tid >> 5;
#pragma unroll
    for (int r = 0; r < 4; ++r)
      tile[r * 8 + ty][tx] = W1[(gg << 16) + (d0 + r * 8 + ty) * 128 + h0 + tx];
    __syncthreads();
#pragma unroll
    for (int r = 0; r < 4; ++r)
      w1t[(gg << 16) + (h0 + r * 8 + ty) * 512 + d0 + tx] =
          f2bf(tile[tx][r * 8 + ty]);
  } else {
#pragma unroll
    for (int j = 0; j < 32; ++j) {
      int i = j * 256 + tid;
      wct[(i & 15) * 512 + (i >> 4)] = f2bf(Wc[i]);
    }
  }
}

// ---------------------------------------------------------------------------
// Fused main kernel (identical to round 1, proven 188us):
//   bid < 512  : logits+softmax block, 128 rows
//   bid >= 512 : expert block, 128x128, XCD-chunked m-major order
// ---------------------------------------------------------------------------
__global__ __launch_bounds__(256, 4) void k_main(
    const unsigned short* __restrict__ zb,
    const unsigned short* __restrict__ w1t,
    const unsigned short* __restrict__ wct, const float* __restrict__ bc,
    const float* __restrict__ b1, const float* __restrict__ w2,
    const float* __restrict__ b2, float* __restrict__ out) {
  __shared__ alignas(16) char lds[33792];
  const int tid = threadIdx.x;
  const int wq = tid >> 6;
  const int l15 = tid & 15;
  const int l4 = (tid >> 4) & 3;
  const int c8s = (((tid & 7) ^ ((tid >> 3) & 7))) * 8;
  if (blockIdx.x >= 512) {
    const int eb = blockIdx.x - 512;
    const int idx = (eb & 7) * 1024 + (eb >> 3);  // XCD-chunked, m-major
    expert_tile(idx & 15, (idx >> 4) * 128, zb, w1t, b1, w2, b2, out, lds, tid,
                wq, l15, l4, c8s);
  } else {
    logits_tile(blockIdx.x * 128, zb, wct, bc, out, lds, tid, wq, l15, l4,
                c8s);
  }
}

// ---------------------------------------------------------------------------
extern "C" void kernel_launch(void* const* d_in, const int* in_sizes, int n_in,
                              void* d_out, int out_size, void* d_ws,
                              size_t ws_size, hipStream_t stream) {
  const float* z = (const float*)d_in[0];
  const float* Wc = (const float*)d_in[1];
  const float* bc = (const float*)d_in[2];
  const float* W1 = (const float*)d_in[3];
  const float* b1 = (const float*)d_in[4];
  const float* W2 = (const float*)d_in[5];
  const float* b2 = (const float*)d_in[6];
  float* out = (float*)d_out;

  unsigned short* zb = (unsigned short*)d_ws;            // 64 MB
  unsigned short* w1t = zb + (size_t)65536 * 512;        // 2 MB
  unsigned short* wct = w1t + (size_t)16 * 128 * 512;    // 16 KB

  k_convert<<<2048 + 1024 + 1, 256, 0, stream>>>(z, W1, Wc, zb, w1t, wct);
  k_main<<<512 + 8192, 256, 0, stream>>>(zb, w1t, wct, bc, b1, W2, b2, out);
}

// Round 5
// 353.648 us; speedup vs baseline: 1.9693x; 1.0393x over previous
//
#include <hip/hip_runtime.h>
#include <cstdint>
#include <cstddef>

typedef __bf16 bf16x8 __attribute__((ext_vector_type(8)));
typedef float f32x4 __attribute__((ext_vector_type(4)));
typedef unsigned short ushortx8 __attribute__((ext_vector_type(8)));

// float -> bf16, round-half-up
__device__ __forceinline__ unsigned short f2bf(float f) {
  union { float f; unsigned int u; } v; v.f = f;
  return (unsigned short)((v.u + 0x8000u) >> 16);
}

// GELU via sigmoid identity (verified in prior rounds)
__device__ __forceinline__ float gelu_s(float x) {
  float x2 = x * x;
  float p = __builtin_fmaf(x2, -0.10294324f, -2.30220819f);
  float e = __builtin_amdgcn_exp2f(x * p);
  return x * __builtin_amdgcn_rcpf(1.0f + e);
}

// async global->LDS, 16B/lane. LDS dest is wave-uniform base + lane*16.
#define GLOAD16(gsrc, ldst)                                                  \
  __builtin_amdgcn_global_load_lds(                                          \
      (const __attribute__((address_space(1))) unsigned int*)(gsrc),         \
      (__attribute__((address_space(3))) unsigned int*)(uintptr_t)(          \
          (char*)(ldst)),                                                    \
      16, 0, 0)

// Swizzled tile: 16B chunk (row R, col8 C in [0,8)) at
// (R>>5)*4096 + ((R&31)*8 + (C ^ (R&7)))*16. Staging lane tid targets chunk
// tid*16 in block it => row=it*32+(tid>>3), dest col8=tid&7, and sources
// global col8 (tid&7)^((tid>>3)&7) so reads SWZ_FRAG(R,C8) see global col C8.
#define SWZ_FRAG(base, R, C8)                                                \
  (*(const bf16x8*)((base) + (((R) >> 5) * 4096) +                           \
                    ((((R)&31) * 8 + ((C8) ^ ((R)&7))) * 16)))

// A-tile staging: z (f32) -> reg -> bf16 -> swizzled LDS. Produces bytes
// bitwise-identical to the old GLOAD16-from-zb path (same f2bf rounding).
// ag = z + (mbase + (tid>>3))*512 + c8s ; writes lds[it*4096 + tid*16].
__device__ __forceinline__ void stage_A_f32(const float* __restrict__ ag,
                                            char* lds, int tid, int ko) {
  f32x4 a0[4], a1[4];
#pragma unroll
  for (int it = 0; it < 4; ++it) {
    const float* p = ag + it * 32 * 512 + ko;
    a0[it] = *(const f32x4*)(p);
    a1[it] = *(const f32x4*)(p + 4);
  }
#pragma unroll
  for (int it = 0; it < 4; ++it) {
    ushortx8 r;
    r[0] = f2bf(a0[it][0]); r[1] = f2bf(a0[it][1]);
    r[2] = f2bf(a0[it][2]); r[3] = f2bf(a0[it][3]);
    r[4] = f2bf(a1[it][0]); r[5] = f2bf(a1[it][1]);
    r[6] = f2bf(a1[it][2]); r[7] = f2bf(a1[it][3]);
    *(ushortx8*)(lds + it * 4096 + tid * 16) = r;
  }
}

// ---------------------------------------------------------------------------
// Tile bodies. A is staged from f32 z directly; B (w1t bf16) via GLOAD16.
// ---------------------------------------------------------------------------
__device__ __forceinline__ void expert_tile(
    int e, int mbase, const float* __restrict__ z,
    const unsigned short* __restrict__ w1t, const float* __restrict__ b1,
    const float* __restrict__ w2, const float* __restrict__ b2,
    float* __restrict__ out, char* lds, int tid, int wq, int l15, int l4,
    int c8s) {
  char* ldsB = lds + 16384;
  const float* ag = z + (size_t)(mbase + (tid >> 3)) * 512 + c8s;
  const unsigned short* bg = w1t + e * 65536 + (tid >> 3) * 512 + c8s;
  const int wr = wq >> 1;  // row half of this wave
  const int wc = wq & 1;   // col half of this wave
  f32x4 acc[4][4] = {};
  for (int kt = 0; kt < 8; ++kt) {
    const int ko = kt * 64;
#pragma unroll
    for (int it = 0; it < 4; ++it)
      GLOAD16(bg + it * 32 * 512 + ko, ldsB + it * 4096 + tid * 16);
    stage_A_f32(ag, lds, tid, ko);
    __syncthreads();
#pragma unroll
    for (int ks = 0; ks < 2; ++ks) {
      bf16x8 af[4];
#pragma unroll
      for (int rt = 0; rt < 4; ++rt)
        af[rt] = SWZ_FRAG(lds, wr * 64 + rt * 16 + l15, ks * 4 + l4);
#pragma unroll
      for (int ct = 0; ct < 4; ++ct) {
        bf16x8 bfv = SWZ_FRAG(ldsB, wc * 64 + ct * 16 + l15, ks * 4 + l4);
#pragma unroll
        for (int rt = 0; rt < 4; ++rt)
          acc[rt][ct] = __builtin_amdgcn_mfma_f32_16x16x32_bf16(
              af[rt], bfv, acc[rt][ct], 0, 0, 0);
      }
    }
    __syncthreads();
  }
  // epilogue: partial y over this wave's 64 cols, cross-wave combine
  float b1v[4], w2v[4];
#pragma unroll
  for (int ct = 0; ct < 4; ++ct) {
    int n = wc * 64 + ct * 16 + l15;
    b1v[ct] = b1[e * 128 + n];
    w2v[ct] = w2[e * 128 + n];
  }
  float* ylds = (float*)(lds + 32768);  // [4 waves][64 rows]
#pragma unroll
  for (int rt = 0; rt < 4; ++rt) {
#pragma unroll
    for (int i = 0; i < 4; ++i) {
      float s = 0.0f;
#pragma unroll
      for (int ct = 0; ct < 4; ++ct)
        s += gelu_s(acc[rt][ct][i] + b1v[ct]) * w2v[ct];
#pragma unroll
      for (int off = 1; off < 16; off <<= 1) s += __shfl_xor(s, off, 16);
      if (l15 == 0) ylds[wq * 64 + rt * 16 + l4 * 4 + i] = s;
    }
  }
  __syncthreads();
  if (tid < 128) {
    int rl = tid & 63, half = tid >> 6;
    float y = ylds[half * 128 + rl] + ylds[half * 128 + 64 + rl] + b2[e];
    out[(size_t)2097152 + (size_t)(mbase + half * 64 + rl) * 16 + e] = y;
  }
}

__device__ __forceinline__ void logits_tile(
    int mbase, const float* __restrict__ z,
    const unsigned short* __restrict__ wct, const float* __restrict__ bc,
    float* __restrict__ out, char* lds, int tid, int wq, int l15, int l4,
    int c8s) {
  const float* ag = z + (size_t)(mbase + (tid >> 3)) * 512 + c8s;
  const unsigned short* wb = wct + l15 * 512 + l4 * 8;  // direct, L2-hot
  f32x4 acc2[2] = {};
  for (int kt = 0; kt < 8; ++kt) {
    const int ko = kt * 64;
    stage_A_f32(ag, lds, tid, ko);
    bf16x8 bfr0 = *(const bf16x8*)(wb + ko);
    bf16x8 bfr1 = *(const bf16x8*)(wb + ko + 32);
    __syncthreads();
#pragma unroll
    for (int rt = 0; rt < 2; ++rt) {
      bf16x8 a0 = SWZ_FRAG(lds, wq * 32 + rt * 16 + l15, l4);
      acc2[rt] =
          __builtin_amdgcn_mfma_f32_16x16x32_bf16(a0, bfr0, acc2[rt], 0, 0, 0);
      bf16x8 a1 = SWZ_FRAG(lds, wq * 32 + rt * 16 + l15, 4 + l4);
      acc2[rt] =
          __builtin_amdgcn_mfma_f32_16x16x32_bf16(a1, bfr1, acc2[rt], 0, 0, 0);
    }
    __syncthreads();
  }
  float bcv = bc[l15];
#pragma unroll
  for (int rt = 0; rt < 2; ++rt) {
#pragma unroll
    for (int i = 0; i < 4; ++i) {
      int row = wq * 32 + rt * 16 + l4 * 4 + i;
      float lg = acc2[rt][i] + bcv;
      float mx = lg;
#pragma unroll
      for (int off = 1; off < 16; off <<= 1)
        mx = fmaxf(mx, __shfl_xor(mx, off, 16));
      float ex = __expf(lg - mx);
      float sm = ex;
#pragma unroll
      for (int off = 1; off < 16; off <<= 1) sm += __shfl_xor(sm, off, 16);
      size_t ro = (size_t)(mbase + row) * 16 + l15;
      out[ro] = lg;                 // logits
      out[1048576 + ro] = ex / sm;  // p_g
    }
  }
}

// ---------------------------------------------------------------------------
// Weight conversion only (z is consumed directly as f32 by k_main now):
//   bid < 1024 : W1[g,d,h] -> W1t[g,h,d] bf16 via 32x32 LDS tile
//   bid == 1024: Wc[d,g] -> Wct[g,d] bf16
// Total ~6 MB of traffic.
// ---------------------------------------------------------------------------
__global__ __launch_bounds__(256) void k_convert(
    const float* __restrict__ W1, const float* __restrict__ Wc,
    unsigned short* __restrict__ w1t, unsigned short* __restrict__ wct) {
  int bid = blockIdx.x;
  int tid = threadIdx.x;
  if (bid < 1024) {
    __shared__ float tile[32][33];
    int gg = bid >> 6;
    int t = bid & 63;  // 16 d-blk x 4 h-blk
    int d0 = (t >> 2) * 32;
    int h0 = (t & 3) * 32;
    int tx = tid & 31, ty = tid >> 5;
#pragma unroll
    for (int r = 0; r < 4; ++r)
      tile[r * 8 + ty][tx] = W1[(gg << 16) + (d0 + r * 8 + ty) * 128 + h0 + tx];
    __syncthreads();
#pragma unroll
    for (int r = 0; r < 4; ++r)
      w1t[(gg << 16) + (h0 + r * 8 + ty) * 512 + d0 + tx] =
          f2bf(tile[tx][r * 8 + ty]);
  } else {
#pragma unroll
    for (int j = 0; j < 32; ++j) {
      int i = j * 256 + tid;
      wct[(i & 15) * 512 + (i >> 4)] = f2bf(Wc[i]);
    }
  }
}

// ---------------------------------------------------------------------------
// Unified main kernel, 8704 blocks = 8 XCDs x 64 panels x 17 tiles.
//   xcd = bid & 7, t = bid >> 3, panel = xcd*64 + t/17, r = t%17.
//   r == 0 -> logits tile; r in [1,16] -> expert tile e = r-1.
// Each panel's 17 tiles run consecutively on ONE XCD: z panel (256 KB f32)
// is HBM-fetched once then L2-served 16x, and the 16 out[row*16+e] partial-
// line writes coalesce in that XCD's L2 (kills the 8x write amplification
// seen in round 4: WRITE_SIZE 102 MB vs 12 MB true output).
// ---------------------------------------------------------------------------
__global__ __launch_bounds__(256, 4) void k_main(
    const float* __restrict__ z, const unsigned short* __restrict__ w1t,
    const unsigned short* __restrict__ wct, const float* __restrict__ bc,
    const float* __restrict__ b1, const float* __restrict__ w2,
    const float* __restrict__ b2, float* __restrict__ out) {
  __shared__ alignas(16) char lds[33792];
  const int tid = threadIdx.x;
  const int wq = tid >> 6;
  const int l15 = tid & 15;
  const int l4 = (tid >> 4) & 3;
  const int c8s = (((tid & 7) ^ ((tid >> 3) & 7))) * 8;
  const int xcd = blockIdx.x & 7;
  const int t = blockIdx.x >> 3;    // 0..1087
  const int pl = t / 17;            // panel-local 0..63
  const int r = t - pl * 17;        // 0..16
  const int mbase = (xcd * 64 + pl) * 128;
  if (r == 0) {
    logits_tile(mbase, z, wct, bc, out, lds, tid, wq, l15, l4, c8s);
  } else {
    expert_tile(r - 1, mbase, z, w1t, b1, w2, b2, out, lds, tid, wq, l15, l4,
                c8s);
  }
}

// ---------------------------------------------------------------------------
extern "C" void kernel_launch(void* const* d_in, const int* in_sizes, int n_in,
                              void* d_out, int out_size, void* d_ws,
                              size_t ws_size, hipStream_t stream) {
  const float* z = (const float*)d_in[0];
  const float* Wc = (const float*)d_in[1];
  const float* bc = (const float*)d_in[2];
  const float* W1 = (const float*)d_in[3];
  const float* b1 = (const float*)d_in[4];
  const float* W2 = (const float*)d_in[5];
  const float* b2 = (const float*)d_in[6];
  float* out = (float*)d_out;

  unsigned short* w1t = (unsigned short*)d_ws;           // 2 MB
  unsigned short* wct = w1t + (size_t)16 * 128 * 512;    // 16 KB

  k_convert<<<1024 + 1, 256, 0, stream>>>(W1, Wc, w1t, wct);
  k_main<<<8 * 1088, 256, 0, stream>>>(z, w1t, wct, bc, b1, W2, b2, out);
}